// Round 2
// baseline (493.524 us; speedup 1.0000x reference)
//
#include <hip/hip_runtime.h>
#include <math.h>

#define BIGNEG (-1000000000.0f)

// Problem-fixed sizes: b=4, N1=512, d=64, C1=32, K=32, C=33, N=513
// ws float offsets
constexpr int OFF_MINV   = 0;        // 64*64 = 4096
constexpr int OFF_LOGDET = 4096;     // 1
constexpr int OFF_Q      = 4100;     // 32*64 = 2048   q[c][t] = Minv @ mean_c
constexpr int OFF_S      = 6148;     // 32             s[c] = mean_c . q[c]
constexpr int OFF_TRANS  = 6180;     // 33*33 = 1089
constexpr int OFF_LENAUG = 7269;     // 32*33 = 1056
constexpr int OFF_INITA  = 8325;     // 33
constexpr int OFF_EOS    = 8358;     // 513
constexpr int OFF_EMLAST = 8871;     // 33
constexpr int OFF_EMT    = 8904;     // 4*32*512 = 65536  (em transposed: [b][c][t])
constexpr int OFF_CSUM   = 74440;    // 4*514*33 = 67848 ; end = 142288 floats (~569 KB)

__device__ __forceinline__ float rl(float x, int l) {
    return __int_as_float(__builtin_amdgcn_readlane(__float_as_int(x), l));
}

// Single-wave register-resident Gauss-Jordan: lane = row, 64+64 cols in VGPRs.
// Pivot-row broadcast via v_readlane (VALU pipe) -> zero LDS traffic, zero
// barriers in the 64-pivot loop (vs 64 __syncthreads + ~380 LDS wave-ops/pivot).
__global__ __launch_bounds__(256) void setup_kernel(
    const float* __restrict__ cov, const float* __restrict__ means,
    const float* __restrict__ plr, const float* __restrict__ tlogits,
    const float* __restrict__ ilogits, const int* __restrict__ lengths,
    float* __restrict__ ws)
{
    __shared__ float A[64][65];      // staging for cov, then holds Minv
    __shared__ float lse_t[32];
    __shared__ float ilse;
    const int tid = threadIdx.x;

    // coalesced cov -> LDS
    for (int idx = tid; idx < 64 * 64; idx += 256)
        A[idx >> 6][idx & 63] = cov[idx];
    __syncthreads();

    if (tid < 64) {                  // wave 0 only: GJ entirely in registers
        const int lane = tid;
        float L[64], R[64];
#pragma unroll
        for (int c = 0; c < 64; ++c) {
            L[c] = A[lane][c];
            R[c] = (lane == c) ? 1.f : 0.f;
        }
        float curcol = L[0];         // column p of left half, per lane
        float myd = 1.f;             // this row's pivot value d_r
#pragma unroll 1
        for (int p = 0; p < 64; ++p) {
            const float d = rl(curcol, p);          // A[p][p]
            const float invd = 1.f / d;
            const float f = (lane == p) ? 0.f : curcol * invd;
            myd = (lane == p) ? d : myd;
            float nextcol = 0.f;
#pragma unroll
            for (int c = 0; c < 64; ++c) {
                const float piv = rl(L[c], p);      // pivot-row broadcast
                L[c] = fmaf(-f, piv, L[c]);
                if (c == p + 1) nextcol = L[c];     // uniform select: next pivot col
            }
#pragma unroll
            for (int c = 0; c < 64; ++c) {
                const float piv = rl(R[c], p);
                R[c] = fmaf(-f, piv, R[c]);
            }
            curcol = nextcol;
        }
        // after 64 pivots: right half = diag(d_r) * Minv  ->  Minv = R / d_r
        const float rdv = 1.f / myd;
#pragma unroll
        for (int c = 0; c < 64; ++c) A[lane][c] = R[c] * rdv;
        // logdet = sum_r log d_r via butterfly reduce
        float lg = logf(myd);
        for (int m = 32; m >= 1; m >>= 1) lg += __shfl_xor(lg, m, 64);
        if (lane == 0) ws[OFF_LOGDET] = lg;
    }
    __syncthreads();

    // Minv -> ws (coalesced); A now holds the final inverse
    for (int idx = tid; idx < 4096; idx += 256)
        ws[OFF_MINV + idx] = A[idx >> 6][idx & 63];
    // q[c][t] = sum_e Minv[t][e] * means[c][e]
    for (int idx = tid; idx < 32 * 64; idx += 256) {
        const int c = idx >> 6, t = idx & 63;
        float acc = 0.f;
        for (int e = 0; e < 64; ++e) acc += A[t][e] * means[c * 64 + e];
        ws[OFF_Q + idx] = acc;
    }
    __syncthreads();
    if (tid < 32) {
        const int c = tid;
        float acc = 0.f;
        for (int t = 0; t < 64; ++t) acc += means[c * 64 + t] * ws[OFF_Q + c * 64 + t];
        ws[OFF_S + c] = acc;
    }
    // column-wise logsumexp of masked transition logits
    if (tid < 32) {
        const int j = tid;
        float mx = -INFINITY;
        for (int i = 0; i < 32; ++i) {
            const float x = (i == j) ? BIGNEG : tlogits[i * 32 + j];
            mx = fmaxf(mx, x);
        }
        float sum = 0.f;
        for (int i = 0; i < 32; ++i) {
            const float x = (i == j) ? BIGNEG : tlogits[i * 32 + j];
            sum += expf(x - mx);
        }
        lse_t[j] = mx + logf(sum);
    }
    if (tid == 0) {
        float mx = -INFINITY;
        for (int i = 0; i < 32; ++i) mx = fmaxf(mx, ilogits[i]);
        float sum = 0.f;
        for (int i = 0; i < 32; ++i) sum += expf(ilogits[i] - mx);
        ilse = mx + logf(sum);
    }
    __syncthreads();
    // trans_aug (33x33): [:32,:32]=trans (diag masked), row 32 = 0, col 32 (rows<32) = BIGNEG
    for (int idx = tid; idx < 1089; idx += 256) {
        const int i = idx / 33, j = idx - i * 33;
        float v;
        if (i == 32) v = 0.f;
        else if (j == 32) v = BIGNEG;
        else if (i == j) v = BIGNEG - lse_t[j];
        else v = tlogits[i * 32 + j] - lse_t[j];
        ws[OFF_TRANS + idx] = v;
    }
    if (tid < 33) ws[OFF_INITA + tid] = (tid < 32) ? (ilogits[tid] - ilse) : BIGNEG;
    // len_aug (32x33)
    for (int idx = tid; idx < 32 * 33; idx += 256) {
        const int k = idx / 33, j = idx - k * 33;
        float v;
        if (j < 32) v = (float)k * plr[j] - expf(plr[j]) - lgammaf((float)k + 1.f);
        else        v = (k == 1) ? 0.f : BIGNEG;
        ws[OFF_LENAUG + idx] = v;
    }
    // eos column (shared across batch, per reference's any() over batches)
    const int l0 = lengths[0], l1 = lengths[1], l2 = lengths[2], l3 = lengths[3];
    for (int t = tid; t < 513; t += 256) {
        const bool any = (l0 == t) | (l1 == t) | (l2 == t) | (l3 == t);
        ws[OFF_EOS + t] = any ? 0.f : BIGNEG;
    }
    // em_last[i] = em_aug[:, 512, i]  (batch-independent)
    if (tid < 33) {
        float v = BIGNEG;
        if (tid == 32) {
            const bool any = (l0 == 512) | (l1 == 512) | (l2 == 512) | (l3 == 512);
            v = any ? 0.f : BIGNEG;
        }
        ws[OFF_EMLAST + tid] = v;
    }
}

// em_t[b][c][n] = -0.5*(f'Minv f - 2 f'q_c + s_c + d*log(2pi) + logdet); one wave per (b,n).
// Result staged through LDS so the global write is 16B-coalesced runs instead of
// 32 isolated dwords (stride-2KB scatter) per wave.
__global__ __launch_bounds__(256) void em_kernel(
    const float* __restrict__ features, float* __restrict__ ws)
{
    __shared__ float sM[64][65];
    __shared__ float sq[32][65];
    __shared__ float sf[4][64];
    __shared__ float ss[32];
    __shared__ float se[4][32];
    const int tid = threadIdx.x;
    for (int idx = tid; idx < 4096; idx += 256) sM[idx >> 6][idx & 63] = ws[OFF_MINV + idx];
    for (int idx = tid; idx < 2048; idx += 256) sq[idx >> 6][idx & 63] = ws[OFF_Q + idx];
    if (tid < 32) ss[tid] = ws[OFF_S + tid];
    const float logdet = ws[OFF_LOGDET];
    const int w = tid >> 6, lane = tid & 63;
    const int p = blockIdx.x * 4 + w;       // (b,n) pair index, b = p>>9, n = p&511
    sf[w][lane] = features[p * 64 + lane];
    __syncthreads();

    float u = 0.f;
    for (int e = 0; e < 64; ++e) u += sM[lane][e] * sf[w][e];
    float a = sf[w][lane] * u;
    for (int m = 32; m >= 1; m >>= 1) a += __shfl_xor(a, m, 64);

    const int c = lane >> 1, h = lane & 1;
    float pd = 0.f;
    const int eb = h * 32;
    for (int e = 0; e < 32; ++e) pd += sf[w][eb + e] * sq[c][eb + e];
    pd += __shfl_xor(pd, 1, 64);

    const float em = -0.5f * (a - 2.f * pd + ss[c] + 64.f * 1.8378770664093453f + logdet);
    if (h == 0) se[w][c] = em;
    __syncthreads();

    // blocks never straddle a batch boundary (512 % 4 == 0)
    if (tid < 128) {
        const int cc = tid >> 2, wv = tid & 3;
        const int p0 = blockIdx.x * 4;
        const int b = p0 >> 9, n0 = p0 & 511;
        ws[OFF_EMT + (b * 32 + cc) * 512 + n0 + wv] = se[wv][cc];
    }
}

// wave-parallel prefix sums: cs[b][0..513][c]. One 64-lane block per (b,c).
__global__ __launch_bounds__(64) void csum_kernel(
    const int* __restrict__ lengths, float* __restrict__ ws)
{
    const int blk = blockIdx.x;
    const int b = blk / 33, c = blk - b * 33;
    const int lane = threadIdx.x;
    const int len = lengths[b];
    const float* emt = ws + OFF_EMT + (b * 32 + c) * 512;
    const float* eos = ws + OFF_EOS;
    const int t0 = lane * 9;            // lanes 0..56 cover t in [0,513)
    float v[9];
#pragma unroll
    for (int i = 0; i < 9; ++i) {
        const int t = t0 + i;
        float x = 0.f;
        if (t <= 512) {
            if (c == 32)      x = eos[t];
            else if (t < 512 && t < len) x = emt[t];
            else              x = BIGNEG;
        }
        v[i] = x;
    }
#pragma unroll
    for (int i = 1; i < 9; ++i) v[i] += v[i - 1];
    const float tot = v[8];
    float inc = tot;
    for (int off = 1; off < 64; off <<= 1) {
        const float y = __shfl_up(inc, off, 64);
        if (lane >= off) inc += y;
    }
    const float excl = inc - tot;
    float* cs = ws + OFF_CSUM + b * 514 * 33 + c;
    if (lane == 0) cs[0] = 0.f;
#pragma unroll
    for (int i = 0; i < 9; ++i) {
        const int t = t0 + i;
        if (t <= 512) cs[(t + 1) * 33] = excl + v[i];
    }
}

// scores[b,t,k,i,j] = trans[i,j] + len_aug[k,j] + wins[b,t,k,j] + t0*init[j] + last*em_last[i]
__global__ __launch_bounds__(256) void score_kernel(
    const float* __restrict__ ws, float* __restrict__ out)
{
    __shared__ float sT[1089];
    __shared__ float sA[32 * 33];
    const int tid = threadIdx.x;
    const int blk = blockIdx.x;
    const int b = blk >> 9, t = blk & 511;
    const float* trans  = ws + OFF_TRANS;
    const float* lenaug = ws + OFF_LENAUG;
    const float* inita  = ws + OFF_INITA;
    const float* emlast = ws + OFF_EMLAST;
    const float* cs     = ws + OFF_CSUM + b * 514 * 33;

    for (int idx = tid; idx < 1089; idx += 256) sT[idx] = trans[idx];
    for (int idx = tid; idx < 1056; idx += 256) {
        const int k = idx / 33, j = idx - k * 33;
        int end = t + k; if (end > 513) end = 513;
        float v = cs[end * 33 + j] - cs[t * 33 + j] + lenaug[idx];
        if (t == 0) v += inita[j];
        sA[idx] = v;
    }
    __syncthreads();

    float tv[5], el[5];
    int jj[5];
#pragma unroll
    for (int m = 0; m < 5; ++m) {
        const int idx = tid + 256 * m;
        if (idx < 1089) {
            const int i = idx / 33;
            jj[m] = idx - i * 33;
            tv[m] = sT[idx];
            el[m] = emlast[i];
        } else { jj[m] = 0; tv[m] = 0.f; el[m] = 0.f; }
    }
    const bool has5 = (tid < 65);
    const int kk = 512 - t;   // the unique k>=1 receiving em_last (if < 32)
    float* ob = out + (size_t)(b * 512 + t) * 32 * 1089;
    for (int k = 0; k < 32; ++k) {
        const float add = (k == kk) ? 1.f : 0.f;
        const float* Ak = sA + k * 33;
        float* op = ob + (size_t)k * 1089;
#pragma unroll
        for (int m = 0; m < 4; ++m)
            __builtin_nontemporal_store(tv[m] + Ak[jj[m]] + add * el[m], op + tid + 256 * m);
        if (has5)
            __builtin_nontemporal_store(tv[4] + Ak[jj[4]] + add * el[4], op + tid + 1024);
    }
}

extern "C" void kernel_launch(void* const* d_in, const int* in_sizes, int n_in,
                              void* d_out, int out_size, void* d_ws, size_t ws_size,
                              hipStream_t stream) {
    (void)in_sizes; (void)n_in; (void)out_size; (void)ws_size;
    const float* features = (const float*)d_in[0];   // (4,512,64)
    const int*   lengths  = (const int*)d_in[1];     // (4,)
    const float* means    = (const float*)d_in[2];   // (32,64)
    const float* cov      = (const float*)d_in[3];   // (64,64)
    const float* plr      = (const float*)d_in[4];   // (32,)
    const float* tlog     = (const float*)d_in[5];   // (32,32)
    const float* ilog     = (const float*)d_in[6];   // (32,)
    float* ws  = (float*)d_ws;
    float* out = (float*)d_out;

    setup_kernel<<<1, 256, 0, stream>>>(cov, means, plr, tlog, ilog, lengths, ws);
    em_kernel<<<512, 256, 0, stream>>>(features, ws);
    csum_kernel<<<132, 64, 0, stream>>>(lengths, ws);
    score_kernel<<<2048, 256, 0, stream>>>(ws, out);
}

// Round 3
// 441.282 us; speedup vs baseline: 1.1184x; 1.1184x over previous
//
#include <hip/hip_runtime.h>
#include <math.h>

#define BIGNEG (-1000000000.0f)

// Problem-fixed sizes: b=4, N1=512, d=64, C1=32, K=32, C=33, N=513
// ws float offsets
constexpr int OFF_MINV   = 0;        // 64*64 = 4096
constexpr int OFF_LOGDET = 4096;     // 1
constexpr int OFF_Q      = 4100;     // 32*64 = 2048   q[c][t] = Minv @ mean_c
constexpr int OFF_S      = 6148;     // 32             s[c] = mean_c . q[c]
constexpr int OFF_TRANS  = 6180;     // 33*33 = 1089
constexpr int OFF_LENAUG = 7269;     // 32*33 = 1056
constexpr int OFF_INITA  = 8325;     // 33
constexpr int OFF_EOS    = 8358;     // 513
constexpr int OFF_EMLAST = 8871;     // 33
constexpr int OFF_EMT    = 8904;     // 4*32*512 = 65536  (em transposed: [b][c][t])
constexpr int OFF_CSUM   = 74440;    // 4*514*33 = 67848 ; end = 142288 floats (~569 KB)

// Blocked (rank-4) Gauss-Jordan on the augmented [cov | I] in LDS.
// Per 4-pivot block: snapshot the 4 pivot rows (Brows), one thread inverts the
// 4x4 pivot block (sBinv = B^{-1}, logdet += log det B), then every row applies
// ONE rank-4 update  row_r -= sum_m coef_r[m] * Brows[m]  with float2 LDS ops.
//   external rows:  coef_r[m] = sum_k A[r][p0+k] * Binv[k][m]
//   block row p0+k: coef[m] = (m==k) ? 0 : -Binv[k][m]/Binv[k][k]
// After 16 blocks the left half is diag(D), right half = D * cov^{-1}, with
// 1/D_r = Binv[k][k] stored in rd[r].  vs per-pivot GJ: 32 barriers instead of
// 64, and ~2x fewer LDS wave-ops (Brows reads are 16-lane broadcasts).
__global__ __launch_bounds__(256) void setup_kernel(
    const float* __restrict__ cov, const float* __restrict__ means,
    const float* __restrict__ plr, const float* __restrict__ tlogits,
    const float* __restrict__ ilogits, const int* __restrict__ lengths,
    float* __restrict__ ws)
{
    __shared__ float A[64][130];
    __shared__ float Brows[4][130];
    __shared__ float sBinv[4][4];
    __shared__ float rd[64];     // 1/D_r
    __shared__ float lgacc;      // logdet accumulator
    __shared__ float lse_t[32];
    __shared__ float ilse;
    const int tid = threadIdx.x;

    for (int idx = tid; idx < 64 * 64; idx += 256) {
        const int r = idx >> 6, c = idx & 63;
        A[r][c] = cov[idx];
        A[r][64 + c] = (r == c) ? 1.f : 0.f;
    }
    if (tid == 0) lgacc = 0.f;
    __syncthreads();

    const int r = tid >> 2;      // row owned (4 threads per row, same wave)
    const int g = tid & 3;
    const int r4 = tid >> 6;     // 0..3 (for Brows copy)
    const int cc = tid & 63;

    for (int blk = 0; blk < 16; ++blk) {
        const int p0 = blk * 4;
        // phase A: snapshot block rows; tid0 inverts the 4x4 pivot block
        Brows[r4][cc]      = A[p0 + r4][cc];
        Brows[r4][cc + 64] = A[p0 + r4][cc + 64];
        if (cc < 2) Brows[r4][cc + 128] = A[p0 + r4][cc + 128];
        if (tid == 0) {
            float B[4][4], V[4][4];
#pragma unroll
            for (int k = 0; k < 4; ++k)
#pragma unroll
                for (int m = 0; m < 4; ++m) {
                    B[k][m] = A[p0 + k][p0 + m];
                    V[k][m] = (k == m) ? 1.f : 0.f;
                }
            float ld = 0.f;
#pragma unroll
            for (int k = 0; k < 4; ++k) {
                const float d = B[k][k];
                ld += logf(d);
                const float invd = 1.f / d;
#pragma unroll
                for (int rr = 0; rr < 4; ++rr) {
                    if (rr == k) continue;
                    const float f = B[rr][k] * invd;
#pragma unroll
                    for (int m = 0; m < 4; ++m) {
                        B[rr][m] = fmaf(-f, B[k][m], B[rr][m]);
                        V[rr][m] = fmaf(-f, V[k][m], V[rr][m]);
                    }
                }
            }
            // V*B_orig = diag(B[k][k])  ->  Binv = diag^-1 * V
#pragma unroll
            for (int k = 0; k < 4; ++k) {
                const float s = 1.f / B[k][k];
#pragma unroll
                for (int m = 0; m < 4; ++m) sBinv[k][m] = V[k][m] * s;
            }
            lgacc += ld;
#pragma unroll
            for (int k = 0; k < 4; ++k) rd[p0 + k] = sBinv[k][k];
        }
        __syncthreads();

        // phase B: rank-4 update of all rows from the snapshot
        float c0, c1, c2, c3;
        if (r >= p0 && r < p0 + 4) {
            const int k = r - p0;
            const float ibkk = 1.f / sBinv[k][k];
            c0 = (k == 0) ? 0.f : -sBinv[k][0] * ibkk;
            c1 = (k == 1) ? 0.f : -sBinv[k][1] * ibkk;
            c2 = (k == 2) ? 0.f : -sBinv[k][2] * ibkk;
            c3 = (k == 3) ? 0.f : -sBinv[k][3] * ibkk;
        } else {
            const float a0 = A[r][p0 + 0], a1 = A[r][p0 + 1];
            const float a2 = A[r][p0 + 2], a3 = A[r][p0 + 3];
            c0 = a0 * sBinv[0][0] + a1 * sBinv[1][0] + a2 * sBinv[2][0] + a3 * sBinv[3][0];
            c1 = a0 * sBinv[0][1] + a1 * sBinv[1][1] + a2 * sBinv[2][1] + a3 * sBinv[3][1];
            c2 = a0 * sBinv[0][2] + a1 * sBinv[1][2] + a2 * sBinv[2][2] + a3 * sBinv[3][2];
            c3 = a0 * sBinv[0][3] + a1 * sBinv[1][3] + a2 * sBinv[2][3] + a3 * sBinv[3][3];
        }
        // NOTE: row r's a_r reads and row r's updates are issued by the same
        // wave (4 threads/row, rows never straddle waves) -> program order
        // keeps them race-free without an extra barrier.
        float2* pa = reinterpret_cast<float2*>(&A[r][0]);
        const float2* pb0 = reinterpret_cast<const float2*>(&Brows[0][0]);
        const float2* pb1 = reinterpret_cast<const float2*>(&Brows[1][0]);
        const float2* pb2 = reinterpret_cast<const float2*>(&Brows[2][0]);
        const float2* pb3 = reinterpret_cast<const float2*>(&Brows[3][0]);
        for (int u = g; u < 65; u += 4) {
            float2 v = pa[u];
            const float2 b0 = pb0[u], b1 = pb1[u], b2 = pb2[u], b3 = pb3[u];
            v.x -= c0 * b0.x + c1 * b1.x + c2 * b2.x + c3 * b3.x;
            v.y -= c0 * b0.y + c1 * b1.y + c2 * b2.y + c3 * b3.y;
            pa[u] = v;
        }
        __syncthreads();
    }

    if (tid == 0) ws[OFF_LOGDET] = lgacc;

    // Minv[r][c] = A[r][64+c] * rd[r]
    for (int idx = tid; idx < 4096; idx += 256) {
        const int row = idx >> 6;
        ws[OFF_MINV + idx] = A[row][64 + (idx & 63)] * rd[row];
    }
    // q[c][t] = sum_e Minv[t][e] * means[c][e]
    for (int idx = tid; idx < 32 * 64; idx += 256) {
        const int c = idx >> 6, t = idx & 63;
        float acc = 0.f;
        for (int e = 0; e < 64; ++e) acc += A[t][64 + e] * means[c * 64 + e];
        ws[OFF_Q + c * 64 + t] = acc * rd[t];
    }
    __syncthreads();
    if (tid < 32) {
        const int c = tid;
        float acc = 0.f;
        for (int t = 0; t < 64; ++t) acc += means[c * 64 + t] * ws[OFF_Q + c * 64 + t];
        ws[OFF_S + c] = acc;
    }
    // column-wise logsumexp of masked transition logits
    if (tid < 32) {
        const int j = tid;
        float mx = -INFINITY;
        for (int i = 0; i < 32; ++i) {
            const float x = (i == j) ? BIGNEG : tlogits[i * 32 + j];
            mx = fmaxf(mx, x);
        }
        float sum = 0.f;
        for (int i = 0; i < 32; ++i) {
            const float x = (i == j) ? BIGNEG : tlogits[i * 32 + j];
            sum += expf(x - mx);
        }
        lse_t[j] = mx + logf(sum);
    }
    if (tid == 0) {
        float mx = -INFINITY;
        for (int i = 0; i < 32; ++i) mx = fmaxf(mx, ilogits[i]);
        float sum = 0.f;
        for (int i = 0; i < 32; ++i) sum += expf(ilogits[i] - mx);
        ilse = mx + logf(sum);
    }
    __syncthreads();
    // trans_aug (33x33): [:32,:32]=trans (diag masked), row 32 = 0, col 32 (rows<32) = BIGNEG
    for (int idx = tid; idx < 1089; idx += 256) {
        const int i = idx / 33, j = idx - i * 33;
        float v;
        if (i == 32) v = 0.f;
        else if (j == 32) v = BIGNEG;
        else if (i == j) v = BIGNEG - lse_t[j];
        else v = tlogits[i * 32 + j] - lse_t[j];
        ws[OFF_TRANS + idx] = v;
    }
    if (tid < 33) ws[OFF_INITA + tid] = (tid < 32) ? (ilogits[tid] - ilse) : BIGNEG;
    // len_aug (32x33)
    for (int idx = tid; idx < 32 * 33; idx += 256) {
        const int k = idx / 33, j = idx - k * 33;
        float v;
        if (j < 32) v = (float)k * plr[j] - expf(plr[j]) - lgammaf((float)k + 1.f);
        else        v = (k == 1) ? 0.f : BIGNEG;
        ws[OFF_LENAUG + idx] = v;
    }
    // eos column (shared across batch, per reference's any() over batches)
    const int l0 = lengths[0], l1 = lengths[1], l2 = lengths[2], l3 = lengths[3];
    for (int t = tid; t < 513; t += 256) {
        const bool any = (l0 == t) | (l1 == t) | (l2 == t) | (l3 == t);
        ws[OFF_EOS + t] = any ? 0.f : BIGNEG;
    }
    // em_last[i] = em_aug[:, 512, i]  (batch-independent)
    if (tid < 33) {
        float v = BIGNEG;
        if (tid == 32) {
            const bool any = (l0 == 512) | (l1 == 512) | (l2 == 512) | (l3 == 512);
            v = any ? 0.f : BIGNEG;
        }
        ws[OFF_EMLAST + tid] = v;
    }
}

// em_t[b][c][n] = -0.5*(f'Minv f - 2 f'q_c + s_c + d*log(2pi) + logdet); one wave per (b,n)
__global__ __launch_bounds__(256) void em_kernel(
    const float* __restrict__ features, float* __restrict__ ws)
{
    __shared__ float sM[64][65];
    __shared__ float sq[32][65];
    __shared__ float sf[4][64];
    __shared__ float ss[32];
    const int tid = threadIdx.x;
    for (int idx = tid; idx < 4096; idx += 256) sM[idx >> 6][idx & 63] = ws[OFF_MINV + idx];
    for (int idx = tid; idx < 2048; idx += 256) sq[idx >> 6][idx & 63] = ws[OFF_Q + idx];
    if (tid < 32) ss[tid] = ws[OFF_S + tid];
    const float logdet = ws[OFF_LOGDET];
    const int w = tid >> 6, lane = tid & 63;
    const int p = blockIdx.x * 4 + w;       // (b,n) pair index, b = p>>9, n = p&511
    sf[w][lane] = features[p * 64 + lane];
    __syncthreads();

    float u = 0.f;
    for (int e = 0; e < 64; ++e) u += sM[lane][e] * sf[w][e];
    float a = sf[w][lane] * u;
    for (int m = 32; m >= 1; m >>= 1) a += __shfl_xor(a, m, 64);

    const int c = lane >> 1, h = lane & 1;
    float pd = 0.f;
    const int eb = h * 32;
    for (int e = 0; e < 32; ++e) pd += sf[w][eb + e] * sq[c][eb + e];
    pd += __shfl_xor(pd, 1, 64);

    const float em = -0.5f * (a - 2.f * pd + ss[c] + 64.f * 1.8378770664093453f + logdet);
    const int b = p >> 9, n = p & 511;
    if (h == 0) ws[OFF_EMT + (b * 32 + c) * 512 + n] = em;
}

// wave-parallel prefix sums: cs[b][0..513][c]. One 64-lane block per (b,c).
__global__ __launch_bounds__(64) void csum_kernel(
    const int* __restrict__ lengths, float* __restrict__ ws)
{
    const int blk = blockIdx.x;
    const int b = blk / 33, c = blk - b * 33;
    const int lane = threadIdx.x;
    const int len = lengths[b];
    const float* emt = ws + OFF_EMT + (b * 32 + c) * 512;
    const float* eos = ws + OFF_EOS;
    const int t0 = lane * 9;            // lanes 0..56 cover t in [0,513)
    float v[9];
#pragma unroll
    for (int i = 0; i < 9; ++i) {
        const int t = t0 + i;
        float x = 0.f;
        if (t <= 512) {
            if (c == 32)      x = eos[t];
            else if (t < 512 && t < len) x = emt[t];
            else              x = BIGNEG;
        }
        v[i] = x;
    }
#pragma unroll
    for (int i = 1; i < 9; ++i) v[i] += v[i - 1];
    const float tot = v[8];
    float inc = tot;
    for (int off = 1; off < 64; off <<= 1) {
        const float y = __shfl_up(inc, off, 64);
        if (lane >= off) inc += y;
    }
    const float excl = inc - tot;
    float* cs = ws + OFF_CSUM + b * 514 * 33 + c;
    if (lane == 0) cs[0] = 0.f;
#pragma unroll
    for (int i = 0; i < 9; ++i) {
        const int t = t0 + i;
        if (t <= 512) cs[(t + 1) * 33] = excl + v[i];
    }
}

// scores[b,t,k,i,j] = trans[i,j] + len_aug[k,j] + wins[b,t,k,j] + t0*init[j] + last*em_last[i]
__global__ __launch_bounds__(256) void score_kernel(
    const float* __restrict__ ws, float* __restrict__ out)
{
    __shared__ float sT[1089];
    __shared__ float sA[32 * 33];
    const int tid = threadIdx.x;
    const int blk = blockIdx.x;
    const int b = blk >> 9, t = blk & 511;
    const float* trans  = ws + OFF_TRANS;
    const float* lenaug = ws + OFF_LENAUG;
    const float* inita  = ws + OFF_INITA;
    const float* emlast = ws + OFF_EMLAST;
    const float* cs     = ws + OFF_CSUM + b * 514 * 33;

    for (int idx = tid; idx < 1089; idx += 256) sT[idx] = trans[idx];
    for (int idx = tid; idx < 1056; idx += 256) {
        const int k = idx / 33, j = idx - k * 33;
        int end = t + k; if (end > 513) end = 513;
        float v = cs[end * 33 + j] - cs[t * 33 + j] + lenaug[idx];
        if (t == 0) v += inita[j];
        sA[idx] = v;
    }
    __syncthreads();

    float tv[5], el[5];
    int jj[5];
#pragma unroll
    for (int m = 0; m < 5; ++m) {
        const int idx = tid + 256 * m;
        if (idx < 1089) {
            const int i = idx / 33;
            jj[m] = idx - i * 33;
            tv[m] = sT[idx];
            el[m] = emlast[i];
        } else { jj[m] = 0; tv[m] = 0.f; el[m] = 0.f; }
    }
    const bool has5 = (tid < 65);
    const int kk = 512 - t;   // the unique k>=1 receiving em_last (if < 32)
    float* ob = out + (size_t)(b * 512 + t) * 32 * 1089;
    for (int k = 0; k < 32; ++k) {
        const float add = (k == kk) ? 1.f : 0.f;
        const float* Ak = sA + k * 33;
        float* op = ob + (size_t)k * 1089;
#pragma unroll
        for (int m = 0; m < 4; ++m)
            __builtin_nontemporal_store(tv[m] + Ak[jj[m]] + add * el[m], op + tid + 256 * m);
        if (has5)
            __builtin_nontemporal_store(tv[4] + Ak[jj[4]] + add * el[4], op + tid + 1024);
    }
}

extern "C" void kernel_launch(void* const* d_in, const int* in_sizes, int n_in,
                              void* d_out, int out_size, void* d_ws, size_t ws_size,
                              hipStream_t stream) {
    (void)in_sizes; (void)n_in; (void)out_size; (void)ws_size;
    const float* features = (const float*)d_in[0];   // (4,512,64)
    const int*   lengths  = (const int*)d_in[1];     // (4,)
    const float* means    = (const float*)d_in[2];   // (32,64)
    const float* cov      = (const float*)d_in[3];   // (64,64)
    const float* plr      = (const float*)d_in[4];   // (32,)
    const float* tlog     = (const float*)d_in[5];   // (32,32)
    const float* ilog     = (const float*)d_in[6];   // (32,)
    float* ws  = (float*)d_ws;
    float* out = (float*)d_out;

    setup_kernel<<<1, 256, 0, stream>>>(cov, means, plr, tlog, ilog, lengths, ws);
    em_kernel<<<512, 256, 0, stream>>>(features, ws);
    csum_kernel<<<132, 64, 0, stream>>>(lengths, ws);
    score_kernel<<<2048, 256, 0, stream>>>(ws, out);
}

// Round 4
// 402.962 us; speedup vs baseline: 1.2247x; 1.0951x over previous
//
#include <hip/hip_runtime.h>
#include <math.h>

#define BIGNEG (-1000000000.0f)

// Problem-fixed sizes: b=4, N1=512, d=64, C1=32, K=32, C=33, N=513
// ws float offsets
constexpr int OFF_MINV   = 0;        // 64*64 = 4096
constexpr int OFF_LOGDET = 4096;     // 1
constexpr int OFF_Q      = 4100;     // 32*64 = 2048   q[c][t] = Minv @ mean_c
constexpr int OFF_S      = 6148;     // 32             s[c] = mean_c . q[c]
constexpr int OFF_TRANS  = 6180;     // 33*33 = 1089
constexpr int OFF_LENAUG = 7269;     // 32*33 = 1056
constexpr int OFF_INITA  = 8325;     // 33
constexpr int OFF_EOS    = 8358;     // 513
constexpr int OFF_EMLAST = 8871;     // 33
constexpr int OFF_EMT    = 8904;     // 4*32*512 = 65536  (em transposed: [b][c][t])
constexpr int OFF_CSUM   = 74440;    // 4*514*33 = 67848 ; end = 142288 floats (~569 KB)

// Setup with an input-adaptive diagonal fast path (correct for ALL inputs):
// while staging cov into LDS each thread flags nonzero off-diagonals; if none,
// Minv = diag(1/d), logdet = sum log d, Q[c][t] = means[c][t]/d_t -- skipping
// the GJ entirely (32 barriers + LDS storm). Non-diagonal inputs fall through
// to the blocked rank-4 Gauss-Jordan (R3 path, -52us vs per-pivot GJ).
__global__ __launch_bounds__(256) void setup_kernel(
    const float* __restrict__ cov, const float* __restrict__ means,
    const float* __restrict__ plr, const float* __restrict__ tlogits,
    const float* __restrict__ ilogits, const int* __restrict__ lengths,
    float* __restrict__ ws)
{
    __shared__ float A[64][130];
    __shared__ float Brows[4][130];
    __shared__ float sBinv[4][4];
    __shared__ float rd[64];     // 1/D_r
    __shared__ float lgacc;      // logdet accumulator
    __shared__ float lse_t[32];
    __shared__ float ilse;
    __shared__ int nondiag;
    const int tid = threadIdx.x;

    if (tid == 0) { lgacc = 0.f; nondiag = 0; }
    __syncthreads();

    int local = 0;
    for (int idx = tid; idx < 64 * 64; idx += 256) {
        const int r = idx >> 6, c = idx & 63;
        const float v = cov[idx];
        A[r][c] = v;
        A[r][64 + c] = (r == c) ? 1.f : 0.f;
        if (r != c && v != 0.f) local = 1;
    }
    if (local) atomicOr(&nondiag, 1);
    __syncthreads();

    if (!nondiag) {
        // ---- diagonal fast path ----
        if (tid < 64) {
            const float d = A[tid][tid];
            rd[tid] = 1.f / d;
            float lg = logf(d);
            for (int m = 32; m >= 1; m >>= 1) lg += __shfl_xor(lg, m, 64);
            if (tid == 0) ws[OFF_LOGDET] = lg;
        }
        __syncthreads();
        for (int idx = tid; idx < 4096; idx += 256) {
            const int row = idx >> 6, col = idx & 63;
            ws[OFF_MINV + idx] = (row == col) ? rd[row] : 0.f;
        }
        // q[c][t] = means[c][t] / d_t
        for (int idx = tid; idx < 32 * 64; idx += 256)
            ws[OFF_Q + idx] = means[idx] * rd[idx & 63];
    } else {
        // ---- general path: blocked (rank-4) Gauss-Jordan on [cov | I] ----
        const int r = tid >> 2;      // row owned (4 threads per row, same wave)
        const int g = tid & 3;
        const int r4 = tid >> 6;     // 0..3 (for Brows copy)
        const int cc = tid & 63;

        for (int blk = 0; blk < 16; ++blk) {
            const int p0 = blk * 4;
            // phase A: snapshot block rows; tid0 inverts the 4x4 pivot block
            Brows[r4][cc]      = A[p0 + r4][cc];
            Brows[r4][cc + 64] = A[p0 + r4][cc + 64];
            if (cc < 2) Brows[r4][cc + 128] = A[p0 + r4][cc + 128];
            if (tid == 0) {
                float B[4][4], V[4][4];
#pragma unroll
                for (int k = 0; k < 4; ++k)
#pragma unroll
                    for (int m = 0; m < 4; ++m) {
                        B[k][m] = A[p0 + k][p0 + m];
                        V[k][m] = (k == m) ? 1.f : 0.f;
                    }
                float ld = 0.f;
#pragma unroll
                for (int k = 0; k < 4; ++k) {
                    const float d = B[k][k];
                    ld += logf(d);
                    const float invd = 1.f / d;
#pragma unroll
                    for (int rr = 0; rr < 4; ++rr) {
                        if (rr == k) continue;
                        const float f = B[rr][k] * invd;
#pragma unroll
                        for (int m = 0; m < 4; ++m) {
                            B[rr][m] = fmaf(-f, B[k][m], B[rr][m]);
                            V[rr][m] = fmaf(-f, V[k][m], V[rr][m]);
                        }
                    }
                }
                // V*B_orig = diag(B[k][k])  ->  Binv = diag^-1 * V
#pragma unroll
                for (int k = 0; k < 4; ++k) {
                    const float s = 1.f / B[k][k];
#pragma unroll
                    for (int m = 0; m < 4; ++m) sBinv[k][m] = V[k][m] * s;
                }
                lgacc += ld;
#pragma unroll
                for (int k = 0; k < 4; ++k) rd[p0 + k] = sBinv[k][k];
            }
            __syncthreads();

            // phase B: rank-4 update of all rows from the snapshot
            float c0, c1, c2, c3;
            if (r >= p0 && r < p0 + 4) {
                const int k = r - p0;
                const float ibkk = 1.f / sBinv[k][k];
                c0 = (k == 0) ? 0.f : -sBinv[k][0] * ibkk;
                c1 = (k == 1) ? 0.f : -sBinv[k][1] * ibkk;
                c2 = (k == 2) ? 0.f : -sBinv[k][2] * ibkk;
                c3 = (k == 3) ? 0.f : -sBinv[k][3] * ibkk;
            } else {
                const float a0 = A[r][p0 + 0], a1 = A[r][p0 + 1];
                const float a2 = A[r][p0 + 2], a3 = A[r][p0 + 3];
                c0 = a0 * sBinv[0][0] + a1 * sBinv[1][0] + a2 * sBinv[2][0] + a3 * sBinv[3][0];
                c1 = a0 * sBinv[0][1] + a1 * sBinv[1][1] + a2 * sBinv[2][1] + a3 * sBinv[3][1];
                c2 = a0 * sBinv[0][2] + a1 * sBinv[1][2] + a2 * sBinv[2][2] + a3 * sBinv[3][2];
                c3 = a0 * sBinv[0][3] + a1 * sBinv[1][3] + a2 * sBinv[2][3] + a3 * sBinv[3][3];
            }
            // row r's a_r reads and its updates are issued by the same wave
            // (4 threads/row, rows never straddle waves) -> program order
            // keeps them race-free without an extra barrier.
            float2* pa = reinterpret_cast<float2*>(&A[r][0]);
            const float2* pb0 = reinterpret_cast<const float2*>(&Brows[0][0]);
            const float2* pb1 = reinterpret_cast<const float2*>(&Brows[1][0]);
            const float2* pb2 = reinterpret_cast<const float2*>(&Brows[2][0]);
            const float2* pb3 = reinterpret_cast<const float2*>(&Brows[3][0]);
            for (int u = g; u < 65; u += 4) {
                float2 v = pa[u];
                const float2 b0 = pb0[u], b1 = pb1[u], b2 = pb2[u], b3 = pb3[u];
                v.x -= c0 * b0.x + c1 * b1.x + c2 * b2.x + c3 * b3.x;
                v.y -= c0 * b0.y + c1 * b1.y + c2 * b2.y + c3 * b3.y;
                pa[u] = v;
            }
            __syncthreads();
        }

        if (tid == 0) ws[OFF_LOGDET] = lgacc;

        // Minv[r][c] = A[r][64+c] * rd[r]
        for (int idx = tid; idx < 4096; idx += 256) {
            const int row = idx >> 6;
            ws[OFF_MINV + idx] = A[row][64 + (idx & 63)] * rd[row];
        }
        // q[c][t] = sum_e Minv[t][e] * means[c][e]
        for (int idx = tid; idx < 32 * 64; idx += 256) {
            const int c = idx >> 6, t = idx & 63;
            float acc = 0.f;
            for (int e = 0; e < 64; ++e) acc += A[t][64 + e] * means[c * 64 + e];
            ws[OFF_Q + c * 64 + t] = acc * rd[t];
        }
    }
    __syncthreads();

    if (tid < 32) {
        const int c = tid;
        float acc = 0.f;
        for (int t = 0; t < 64; ++t) acc += means[c * 64 + t] * ws[OFF_Q + c * 64 + t];
        ws[OFF_S + c] = acc;
    }
    // column-wise logsumexp of masked transition logits
    if (tid < 32) {
        const int j = tid;
        float mx = -INFINITY;
        for (int i = 0; i < 32; ++i) {
            const float x = (i == j) ? BIGNEG : tlogits[i * 32 + j];
            mx = fmaxf(mx, x);
        }
        float sum = 0.f;
        for (int i = 0; i < 32; ++i) {
            const float x = (i == j) ? BIGNEG : tlogits[i * 32 + j];
            sum += expf(x - mx);
        }
        lse_t[j] = mx + logf(sum);
    }
    if (tid == 0) {
        float mx = -INFINITY;
        for (int i = 0; i < 32; ++i) mx = fmaxf(mx, ilogits[i]);
        float sum = 0.f;
        for (int i = 0; i < 32; ++i) sum += expf(ilogits[i] - mx);
        ilse = mx + logf(sum);
    }
    __syncthreads();
    // trans_aug (33x33): [:32,:32]=trans (diag masked), row 32 = 0, col 32 (rows<32) = BIGNEG
    for (int idx = tid; idx < 1089; idx += 256) {
        const int i = idx / 33, j = idx - i * 33;
        float v;
        if (i == 32) v = 0.f;
        else if (j == 32) v = BIGNEG;
        else if (i == j) v = BIGNEG - lse_t[j];
        else v = tlogits[i * 32 + j] - lse_t[j];
        ws[OFF_TRANS + idx] = v;
    }
    if (tid < 33) ws[OFF_INITA + tid] = (tid < 32) ? (ilogits[tid] - ilse) : BIGNEG;
    // len_aug (32x33)
    for (int idx = tid; idx < 32 * 33; idx += 256) {
        const int k = idx / 33, j = idx - k * 33;
        float v;
        if (j < 32) v = (float)k * plr[j] - expf(plr[j]) - lgammaf((float)k + 1.f);
        else        v = (k == 1) ? 0.f : BIGNEG;
        ws[OFF_LENAUG + idx] = v;
    }
    // eos column (shared across batch, per reference's any() over batches)
    const int l0 = lengths[0], l1 = lengths[1], l2 = lengths[2], l3 = lengths[3];
    for (int t = tid; t < 513; t += 256) {
        const bool any = (l0 == t) | (l1 == t) | (l2 == t) | (l3 == t);
        ws[OFF_EOS + t] = any ? 0.f : BIGNEG;
    }
    // em_last[i] = em_aug[:, 512, i]  (batch-independent)
    if (tid < 33) {
        float v = BIGNEG;
        if (tid == 32) {
            const bool any = (l0 == 512) | (l1 == 512) | (l2 == 512) | (l3 == 512);
            v = any ? 0.f : BIGNEG;
        }
        ws[OFF_EMLAST + tid] = v;
    }
}

// em_t[b][c][n] = -0.5*(f'Minv f - 2 f'q_c + s_c + d*log(2pi) + logdet); one wave per (b,n)
__global__ __launch_bounds__(256) void em_kernel(
    const float* __restrict__ features, float* __restrict__ ws)
{
    __shared__ float sM[64][65];
    __shared__ float sq[32][65];
    __shared__ float sf[4][64];
    __shared__ float ss[32];
    const int tid = threadIdx.x;
    for (int idx = tid; idx < 4096; idx += 256) sM[idx >> 6][idx & 63] = ws[OFF_MINV + idx];
    for (int idx = tid; idx < 2048; idx += 256) sq[idx >> 6][idx & 63] = ws[OFF_Q + idx];
    if (tid < 32) ss[tid] = ws[OFF_S + tid];
    const float logdet = ws[OFF_LOGDET];
    const int w = tid >> 6, lane = tid & 63;
    const int p = blockIdx.x * 4 + w;       // (b,n) pair index, b = p>>9, n = p&511
    sf[w][lane] = features[p * 64 + lane];
    __syncthreads();

    float u = 0.f;
    for (int e = 0; e < 64; ++e) u += sM[lane][e] * sf[w][e];
    float a = sf[w][lane] * u;
    for (int m = 32; m >= 1; m >>= 1) a += __shfl_xor(a, m, 64);

    const int c = lane >> 1, h = lane & 1;
    float pd = 0.f;
    const int eb = h * 32;
    for (int e = 0; e < 32; ++e) pd += sf[w][eb + e] * sq[c][eb + e];
    pd += __shfl_xor(pd, 1, 64);

    const float em = -0.5f * (a - 2.f * pd + ss[c] + 64.f * 1.8378770664093453f + logdet);
    const int b = p >> 9, n = p & 511;
    if (h == 0) ws[OFF_EMT + (b * 32 + c) * 512 + n] = em;
}

// wave-parallel prefix sums: cs[b][0..513][c]. One 64-lane block per (b,c).
__global__ __launch_bounds__(64) void csum_kernel(
    const int* __restrict__ lengths, float* __restrict__ ws)
{
    const int blk = blockIdx.x;
    const int b = blk / 33, c = blk - b * 33;
    const int lane = threadIdx.x;
    const int len = lengths[b];
    const float* emt = ws + OFF_EMT + (b * 32 + c) * 512;
    const float* eos = ws + OFF_EOS;
    const int t0 = lane * 9;            // lanes 0..56 cover t in [0,513)
    float v[9];
#pragma unroll
    for (int i = 0; i < 9; ++i) {
        const int t = t0 + i;
        float x = 0.f;
        if (t <= 512) {
            if (c == 32)      x = eos[t];
            else if (t < 512 && t < len) x = emt[t];
            else              x = BIGNEG;
        }
        v[i] = x;
    }
#pragma unroll
    for (int i = 1; i < 9; ++i) v[i] += v[i - 1];
    const float tot = v[8];
    float inc = tot;
    for (int off = 1; off < 64; off <<= 1) {
        const float y = __shfl_up(inc, off, 64);
        if (lane >= off) inc += y;
    }
    const float excl = inc - tot;
    float* cs = ws + OFF_CSUM + b * 514 * 33 + c;
    if (lane == 0) cs[0] = 0.f;
#pragma unroll
    for (int i = 0; i < 9; ++i) {
        const int t = t0 + i;
        if (t <= 512) cs[(t + 1) * 33] = excl + v[i];
    }
}

// scores[b,t,k,i,j] = trans[i,j] + len_aug[k,j] + wins[b,t,k,j] + t0*init[j] + last*em_last[i]
__global__ __launch_bounds__(256) void score_kernel(
    const float* __restrict__ ws, float* __restrict__ out)
{
    __shared__ float sT[1089];
    __shared__ float sA[32 * 33];
    const int tid = threadIdx.x;
    const int blk = blockIdx.x;
    const int b = blk >> 9, t = blk & 511;
    const float* trans  = ws + OFF_TRANS;
    const float* lenaug = ws + OFF_LENAUG;
    const float* inita  = ws + OFF_INITA;
    const float* emlast = ws + OFF_EMLAST;
    const float* cs     = ws + OFF_CSUM + b * 514 * 33;

    for (int idx = tid; idx < 1089; idx += 256) sT[idx] = trans[idx];
    for (int idx = tid; idx < 1056; idx += 256) {
        const int k = idx / 33, j = idx - k * 33;
        int end = t + k; if (end > 513) end = 513;
        float v = cs[end * 33 + j] - cs[t * 33 + j] + lenaug[idx];
        if (t == 0) v += inita[j];
        sA[idx] = v;
    }
    __syncthreads();

    float tv[5], el[5];
    int jj[5];
#pragma unroll
    for (int m = 0; m < 5; ++m) {
        const int idx = tid + 256 * m;
        if (idx < 1089) {
            const int i = idx / 33;
            jj[m] = idx - i * 33;
            tv[m] = sT[idx];
            el[m] = emlast[i];
        } else { jj[m] = 0; tv[m] = 0.f; el[m] = 0.f; }
    }
    const bool has5 = (tid < 65);
    const int kk = 512 - t;   // the unique k>=1 receiving em_last (if < 32)
    float* ob = out + (size_t)(b * 512 + t) * 32 * 1089;
    for (int k = 0; k < 32; ++k) {
        const float add = (k == kk) ? 1.f : 0.f;
        const float* Ak = sA + k * 33;
        float* op = ob + (size_t)k * 1089;
#pragma unroll
        for (int m = 0; m < 4; ++m)
            __builtin_nontemporal_store(tv[m] + Ak[jj[m]] + add * el[m], op + tid + 256 * m);
        if (has5)
            __builtin_nontemporal_store(tv[4] + Ak[jj[4]] + add * el[4], op + tid + 1024);
    }
}

extern "C" void kernel_launch(void* const* d_in, const int* in_sizes, int n_in,
                              void* d_out, int out_size, void* d_ws, size_t ws_size,
                              hipStream_t stream) {
    (void)in_sizes; (void)n_in; (void)out_size; (void)ws_size;
    const float* features = (const float*)d_in[0];   // (4,512,64)
    const int*   lengths  = (const int*)d_in[1];     // (4,)
    const float* means    = (const float*)d_in[2];   // (32,64)
    const float* cov      = (const float*)d_in[3];   // (64,64)
    const float* plr      = (const float*)d_in[4];   // (32,)
    const float* tlog     = (const float*)d_in[5];   // (32,32)
    const float* ilog     = (const float*)d_in[6];   // (32,)
    float* ws  = (float*)d_ws;
    float* out = (float*)d_out;

    setup_kernel<<<1, 256, 0, stream>>>(cov, means, plr, tlog, ilog, lengths, ws);
    em_kernel<<<512, 256, 0, stream>>>(features, ws);
    csum_kernel<<<132, 64, 0, stream>>>(lengths, ws);
    score_kernel<<<2048, 256, 0, stream>>>(ws, out);
}